// Round 6
// baseline (121.573 us; speedup 1.0000x reference)
//
#include <hip/hip_runtime.h>
#include <math.h>

// Problem constants
#define BSZ   512
#define XD    768
#define YD    128
#define H2D   512

// ---------------------------------------------------------------------------
// layer1: split-K x16 partials of x @ W1, both branches. NO bias/relu
// (applied in layer2 staging). x:(512,768) W1:(768,512)
//   -> p1[br*16+ks][512][512]  (32 slices, 32 MB).
// Tile 128x128, 8x8 per thread (64 FMA per 64 B LDS = 1 FMA/B, the LDS
// balance point), K-tile 16, K-chunk 48. Grid (4,4,32) = 512 blocks ->
// 2 blocks/CU. LDS: As[k][m] (scatter), Bs[k][n] (direct b128), stride 132.
// a-reads are 4-unique-address (bank-disjoint) broadcasts; b-reads have a
// structural 4-way bank alias (accepted).
// ---------------------------------------------------------------------------
__global__ __launch_bounds__(256, 2) void layer1_kernel(
    const float* __restrict__ x,
    const float* __restrict__ w1_mu, const float* __restrict__ w1_lv,
    float* __restrict__ p1)
{
    __shared__ float As[16][132];
    __shared__ float Bs[16][132];

    const int t      = threadIdx.x;
    const int branch = blockIdx.z >> 4;
    const int ks     = blockIdx.z & 15;
    const float* __restrict__ W = branch ? w1_lv : w1_mu;
    float* __restrict__ out = p1 + (size_t)blockIdx.z * (BSZ * H2D);

    const int m0 = blockIdx.x * 128;
    const int n0 = blockIdx.y * 128;
    const int tx = t & 15;          // 8 n-cols at tx*8
    const int ty = t >> 4;          // 8 m-rows at ty*8

    // staging maps: A 128m x 16k (2 float4/thread), B 16k x 128n (2 float4)
    const int am  = t >> 1;         // 0..127
    const int akq = (t & 1) * 8;    // 0 or 8
    const int bkk = t >> 4;         // 0..15
    const int bnq = (t & 15) * 8;   // 0..120

    const int kbase = ks * 48;
    float acc[8][8] = {};

    float4 a0p = *(const float4*)&x[(m0 + am) * XD + kbase + akq];
    float4 a1p = *(const float4*)&x[(m0 + am) * XD + kbase + akq + 4];
    float4 b0p = *(const float4*)&W[(kbase + bkk) * H2D + n0 + bnq];
    float4 b1p = *(const float4*)&W[(kbase + bkk) * H2D + n0 + bnq + 4];

    for (int kt = 0; kt < 48; kt += 16) {
        __syncthreads();            // prev tile's readers done
        As[akq + 0][am] = a0p.x; As[akq + 1][am] = a0p.y;
        As[akq + 2][am] = a0p.z; As[akq + 3][am] = a0p.w;
        As[akq + 4][am] = a1p.x; As[akq + 5][am] = a1p.y;
        As[akq + 6][am] = a1p.z; As[akq + 7][am] = a1p.w;
        *(float4*)&Bs[bkk][bnq]     = b0p;
        *(float4*)&Bs[bkk][bnq + 4] = b1p;
        __syncthreads();
        if (kt + 16 < 48) {         // prefetch next tile under the FMAs
            const int kn = kbase + kt + 16;
            a0p = *(const float4*)&x[(m0 + am) * XD + kn + akq];
            a1p = *(const float4*)&x[(m0 + am) * XD + kn + akq + 4];
            b0p = *(const float4*)&W[(kn + bkk) * H2D + n0 + bnq];
            b1p = *(const float4*)&W[(kn + bkk) * H2D + n0 + bnq + 4];
        }
        #pragma unroll
        for (int k = 0; k < 16; ++k) {
            const float4 a0 = *(const float4*)&As[k][ty * 8];
            const float4 a1 = *(const float4*)&As[k][ty * 8 + 4];
            const float4 b0 = *(const float4*)&Bs[k][tx * 8];
            const float4 b1 = *(const float4*)&Bs[k][tx * 8 + 4];
            const float av[8] = {a0.x, a0.y, a0.z, a0.w, a1.x, a1.y, a1.z, a1.w};
            const float bv[8] = {b0.x, b0.y, b0.z, b0.w, b1.x, b1.y, b1.z, b1.w};
            #pragma unroll
            for (int i = 0; i < 8; ++i)
                #pragma unroll
                for (int j = 0; j < 8; ++j)
                    acc[i][j] += av[i] * bv[j];
        }
    }

    #pragma unroll
    for (int i = 0; i < 8; ++i) {
        const int row = (m0 + ty * 8 + i) * H2D + n0 + tx * 8;
        *(float4*)&out[row]     = make_float4(acc[i][0], acc[i][1], acc[i][2], acc[i][3]);
        *(float4*)&out[row + 4] = make_float4(acc[i][4], acc[i][5], acc[i][6], acc[i][7]);
    }
}

// ---------------------------------------------------------------------------
// layer2 (B-stationary, + ysum plane): split-K x16 partials of
// relu(sum_16 p1 + b1) @ W2 -> p2[br*16+ks2][512][128] (32 slices, 8 MB).
// Block = 32 m-rows x full N=128, K-chunk 32. Grid (16,1,33):
//   z<32: branch=z>>4, ks2=z&15.  z==32: ysum plane (Sy/Sy2 + acc init).
// W2-chunk lives in REGISTERS (2 cols/lane x 32 k = 64 VGPR; coalesced
// global loads, L2-hot). H-chunk (32x32) staged once in LDS (16-slice sum +
// bias + relu), then read as wave-uniform broadcast b128 (256 LDS reads per
// block total). Each wave owns 8 m-rows; 512 FMA/lane.
// ---------------------------------------------------------------------------
__global__ __launch_bounds__(256, 2) void layer2_kernel(
    const float* __restrict__ p1,
    const float* __restrict__ b1_mu, const float* __restrict__ b1_lv,
    const float* __restrict__ w2_mu, const float* __restrict__ w2_lv,
    const float* __restrict__ y,
    float* __restrict__ p2,
    double* __restrict__ Sy, double* __restrict__ Sy2,
    double* __restrict__ accum, unsigned int* __restrict__ counter)
{
    __shared__ float Hc[32][36];    // 32 m x 32 k, +4 pad
    const int t = threadIdx.x;

    if (blockIdx.z == 32) {
        // ----- ysum plane: 16 blocks, 8 dims each -----
        const int id = blockIdx.x;
        const int dl = t & 7;
        const int g  = t >> 3;               // 0..31, 16 rows each
        const int d  = id * 8 + dl;
        float s = 0.f, s2 = 0.f;
        #pragma unroll
        for (int i = g * 16; i < g * 16 + 16; ++i) {
            const float v = y[i * YD + d];
            s += v; s2 += v * v;
        }
        float* shs  = &Hc[0][0];             // 1152 floats available
        float* shs2 = &Hc[0][0] + 512;
        shs[t] = s; shs2[t] = s2;
        __syncthreads();
        if (t < 8) {
            double S = 0.0, S2 = 0.0;
            #pragma unroll
            for (int gg = 0; gg < 32; ++gg) {
                S += (double)shs[gg * 8 + t]; S2 += (double)shs2[gg * 8 + t];
            }
            Sy[id * 8 + t] = S; Sy2[id * 8 + t] = S2;
        } else if (id == 0 && t == 8)  { accum[0] = 0.0; }
        else if (id == 0 && t == 9)  { accum[1] = 0.0; }
        else if (id == 0 && t == 10) { *counter = 0u; }
        return;
    }

    // ----- GEMM planes -----
    const int branch = blockIdx.z >> 4;
    const int ks2    = blockIdx.z & 15;
    const float* __restrict__ q  = p1 + (size_t)(branch * 16) * (BSZ * H2D);
    const float* __restrict__ b1 = branch ? b1_lv : b1_mu;
    const float* __restrict__ W  = branch ? w2_lv : w2_mu;
    float* __restrict__ out = p2 + (size_t)blockIdx.z * (BSZ * YD);

    const int m0   = blockIdx.x * 32;
    const int kb   = ks2 * 32;
    const int lane = t & 63;
    const int wave = t >> 6;

    // B chunk into registers: 2 cols (lane, 64+lane) x 32 k.
    float br0[32], br1[32];
    #pragma unroll
    for (int k = 0; k < 32; ++k) {
        br0[k] = W[(kb + k) * YD + lane];
        br1[k] = W[(kb + k) * YD + 64 + lane];
    }

    // Stage H chunk: row = t>>3 (0..31), kq = (t&7)*4. Sum 16 p1 slices +
    // bias, relu, write b128.
    {
        const int row = t >> 3;
        const int kq  = (t & 7) * 4;
        const int base = (m0 + row) * H2D + kb + kq;
        float4 h = *(const float4*)&b1[kb + kq];
        #pragma unroll
        for (int s = 0; s < 16; ++s) {
            const float4 v = *(const float4*)&q[(size_t)s * (BSZ * H2D) + base];
            h.x += v.x; h.y += v.y; h.z += v.z; h.w += v.w;
        }
        h.x = fmaxf(h.x, 0.f); h.y = fmaxf(h.y, 0.f);
        h.z = fmaxf(h.z, 0.f); h.w = fmaxf(h.w, 0.f);
        *(float4*)&Hc[row][kq] = h;
    }
    __syncthreads();

    // Compute: wave owns m-rows wave*8 .. wave*8+7; a-reads are wave-uniform
    // broadcasts.
    const int wm0 = wave * 8;
    float acc0[8] = {}, acc1[8] = {};
    #pragma unroll
    for (int m = 0; m < 8; ++m) {
        const float* hrow = &Hc[wm0 + m][0];
        #pragma unroll
        for (int qd = 0; qd < 8; ++qd) {
            const float4 a4 = *(const float4*)&hrow[qd * 4];
            acc0[m] += a4.x * br0[qd * 4 + 0]; acc1[m] += a4.x * br1[qd * 4 + 0];
            acc0[m] += a4.y * br0[qd * 4 + 1]; acc1[m] += a4.y * br1[qd * 4 + 1];
            acc0[m] += a4.z * br0[qd * 4 + 2]; acc1[m] += a4.z * br1[qd * 4 + 2];
            acc0[m] += a4.w * br0[qd * 4 + 3]; acc1[m] += a4.w * br1[qd * 4 + 3];
        }
    }

    #pragma unroll
    for (int m = 0; m < 8; ++m) {
        const int row = (m0 + wm0 + m) * YD;
        out[row + lane]      = acc0[m];
        out[row + 64 + lane] = acc1[m];
    }
}

// ---------------------------------------------------------------------------
// reduce (+inline finalize): per element e=(i,d):
//   mu = sum_{s<16} p2[s][e] + b2_mu[d]; lv = tanh(sum_{s>=16} p2[s][e] + b2_lv[d])
//   iv = exp(-lv)
//   pos += -0.5*(mu-y)^2*iv - 0.5*lv
//   ap  += iv*(-0.5*Sy2[d] + mu*Sy[d] - 256*mu^2) - 256*lv
// fp32 elementwise, fp64 block reduction + device atomics; last block (atomic
// counter) finalizes: out = pos/B - ap/B^2 - log1p(exp(-20)/(B-1)).
// ---------------------------------------------------------------------------
__global__ __launch_bounds__(256) void reduce_kernel(
    const float* __restrict__ p2, const float* __restrict__ y,
    const float* __restrict__ b2_mu, const float* __restrict__ b2_lv,
    const double* __restrict__ Sy, const double* __restrict__ Sy2,
    double* __restrict__ accum, unsigned int* __restrict__ counter,
    float* __restrict__ outp)
{
    const int NE = BSZ * YD;
    const int e  = blockIdx.x * 256 + threadIdx.x;   // grid 256 covers exactly
    const int d  = e & (YD - 1);

    float mu = b2_mu[d];
    float lp = b2_lv[d];
    #pragma unroll
    for (int s = 0; s < 16; ++s) {
        mu += p2[s * NE + e];
        lp += p2[(16 + s) * NE + e];
    }
    const float lv = tanhf(lp);
    const float iv = expf(-lv);
    const float dm = mu - y[e];

    double pos = -0.5 * (double)dm * (double)dm * (double)iv - 0.5 * (double)lv;
    double ap  = (double)iv * (-0.5 * Sy2[d] + (double)mu * Sy[d]
                               - 256.0 * (double)mu * (double)mu)
               - 256.0 * (double)lv;

    #pragma unroll
    for (int off = 32; off > 0; off >>= 1) {
        pos += __shfl_down(pos, off);
        ap  += __shfl_down(ap, off);
    }
    __shared__ double sp[4];
    __shared__ double sa[4];
    const int lane = threadIdx.x & 63;
    const int wv   = threadIdx.x >> 6;
    if (lane == 0) { sp[wv] = pos; sa[wv] = ap; }
    __syncthreads();
    if (threadIdx.x == 0) {
        atomicAdd(&accum[0], sp[0] + sp[1] + sp[2] + sp[3]);
        atomicAdd(&accum[1], sa[0] + sa[1] + sa[2] + sa[3]);
        __threadfence();
        const unsigned int old = atomicAdd(counter, 1u);
        if (old == 255u) {                 // last block: finalize
            const double P = atomicAdd(&accum[0], 0.0);   // coherent read-back
            const double A = atomicAdd(&accum[1], 0.0);
            const double C = log1p(exp(-20.0) / 511.0);
            outp[0] = (float)(P / 512.0 - A / 262144.0 - C);
        }
    }
}

extern "C" void kernel_launch(void* const* d_in, const int* in_sizes, int n_in,
                              void* d_out, int out_size, void* d_ws, size_t ws_size,
                              hipStream_t stream) {
    const float* x     = (const float*)d_in[0];
    const float* y     = (const float*)d_in[1];
    const float* w1_mu = (const float*)d_in[2];
    const float* b1_mu = (const float*)d_in[3];
    const float* w2_mu = (const float*)d_in[4];
    const float* b2_mu = (const float*)d_in[5];
    const float* w1_lv = (const float*)d_in[6];
    const float* b1_lv = (const float*)d_in[7];
    const float* w2_lv = (const float*)d_in[8];
    const float* b2_lv = (const float*)d_in[9];

    char* ws = (char*)d_ws;
    float*  p1 = (float*)(ws);                                     // 32 MB (32 slices 512x512)
    float*  p2 = (float*)(ws + (size_t)32 * BSZ * H2D * 4);        // 8 MB (32 slices 512x128)
    double* Sy = (double*)(ws + (size_t)32 * BSZ * H2D * 4
                              + (size_t)32 * BSZ * YD * 4);        // 1 KB
    double* Sy2 = Sy + YD;                                         // 1 KB
    double* accum = Sy2 + YD;                                      // 16 B
    unsigned int* counter = (unsigned int*)(accum + 2);            // 4 B

    layer1_kernel<<<dim3(4, 4, 32), 256, 0, stream>>>(x, w1_mu, w1_lv, p1);
    layer2_kernel<<<dim3(16, 1, 33), 256, 0, stream>>>(
        p1, b1_mu, b1_lv, w2_mu, w2_lv, y, p2, Sy, Sy2, accum, counter);
    reduce_kernel<<<256, 256, 0, stream>>>(
        p2, y, b2_mu, b2_lv, Sy, Sy2, accum, counter, (float*)d_out);
}

// Round 7
// 111.530 us; speedup vs baseline: 1.0900x; 1.0900x over previous
//
#include <hip/hip_runtime.h>
#include <math.h>

// Problem constants
#define BSZ   512
#define XD    768
#define YD    128
#define H2D   512

// Cost model note (R6 post-mortem): the harness re-poisons the FULL d_ws
// every timed iteration; each MB of workspace my kernels dirty costs
// ~0.17 us extra in that fill (dirty-line eviction). Keep ws writes minimal:
// p1 = 8 MB, p2 = 4 MB, total 12 MB.

// ---------------------------------------------------------------------------
// layer1: split-K x4 partials of x @ W1, both branches. NO bias/relu
// (applied in layer2 staging). x:(512,768) W1:(768,512)
//   -> p1[branch*4+ks][512][512]  (8 slices, 8 MB).
// Tile 64x64, 4x4 per thread, K-tile 16, K-chunk 192. Grid (8,8,8) = 512
// blocks -> 2 blocks/CU (co-resident block hides barrier drains).
// LDS: As[k][m], Bs[k][n], stride 68. a-reads = 4-addr broadcast (free),
// b-reads = 2-way (free), staging scatter 2-way (free).
// ---------------------------------------------------------------------------
__global__ __launch_bounds__(256, 2) void layer1_kernel(
    const float* __restrict__ x,
    const float* __restrict__ w1_mu, const float* __restrict__ w1_lv,
    float* __restrict__ p1)
{
    __shared__ float As[16][68];
    __shared__ float Bs[16][68];

    const int t      = threadIdx.x;
    const int branch = blockIdx.z >> 2;
    const int ks     = blockIdx.z & 3;
    const float* __restrict__ W = branch ? w1_lv : w1_mu;
    float* __restrict__ out = p1 + (size_t)blockIdx.z * (BSZ * H2D);

    const int m0 = blockIdx.x * 64;
    const int n0 = blockIdx.y * 64;
    const int tx = t & 15;          // 4 n-cols at tx*4
    const int ty = t >> 4;          // 4 m-rows at ty*4

    // staging maps: A 64m x 16k (1 float4/thread), B 16k x 64n (1 float4)
    const int am  = t >> 2;         // 0..63
    const int akq = (t & 3) * 4;    // 0,4,8,12
    const int bkk = t >> 4;         // 0..15
    const int bnq = (t & 15) * 4;   // 0..60

    const int kbase = ks * 192;
    float acc[4][4] = {};

    float4 ap = *(const float4*)&x[(m0 + am) * XD + kbase + akq];
    float4 bp = *(const float4*)&W[(kbase + bkk) * H2D + n0 + bnq];

    for (int kt = 0; kt < 192; kt += 16) {
        __syncthreads();            // prev tile's readers done
        As[akq + 0][am] = ap.x; As[akq + 1][am] = ap.y;
        As[akq + 2][am] = ap.z; As[akq + 3][am] = ap.w;
        *(float4*)&Bs[bkk][bnq] = bp;
        __syncthreads();
        if (kt + 16 < 192) {        // prefetch next tile under the FMAs
            const int kn = kbase + kt + 16;
            ap = *(const float4*)&x[(m0 + am) * XD + kn + akq];
            bp = *(const float4*)&W[(kn + bkk) * H2D + n0 + bnq];
        }
        #pragma unroll
        for (int k = 0; k < 16; ++k) {
            const float4 a4 = *(const float4*)&As[k][ty * 4];
            const float4 b4 = *(const float4*)&Bs[k][tx * 4];
            acc[0][0] += a4.x*b4.x; acc[0][1] += a4.x*b4.y; acc[0][2] += a4.x*b4.z; acc[0][3] += a4.x*b4.w;
            acc[1][0] += a4.y*b4.x; acc[1][1] += a4.y*b4.y; acc[1][2] += a4.y*b4.z; acc[1][3] += a4.y*b4.w;
            acc[2][0] += a4.z*b4.x; acc[2][1] += a4.z*b4.y; acc[2][2] += a4.z*b4.z; acc[2][3] += a4.z*b4.w;
            acc[3][0] += a4.w*b4.x; acc[3][1] += a4.w*b4.y; acc[3][2] += a4.w*b4.z; acc[3][3] += a4.w*b4.w;
        }
    }

    #pragma unroll
    for (int i = 0; i < 4; ++i) {
        const float4 o = make_float4(acc[i][0], acc[i][1], acc[i][2], acc[i][3]);
        *(float4*)&out[(m0 + ty * 4 + i) * H2D + n0 + tx * 4] = o;
    }
}

// ---------------------------------------------------------------------------
// layer2 (B-stationary, + ysum plane): split-K x8 partials of
// relu(sum_4 p1 + b1) @ W2 -> p2[branch*8+ks][512][128] (16 slices, 4 MB).
// Block = 32 m-rows x full N=128, K-chunk 64 processed as two 32-k register
// sub-chunks (B-regs: 2 cols/lane x 32 k = 64 VGPR, coalesced L2-hot loads).
// H-chunk (32x64) staged ONCE in LDS (4-slice sum + bias + relu), read as
// wave-uniform broadcast b128. One barrier per block -> 1 block/CU is OK.
// Grid (16,1,17): z<16 GEMM (branch=z>>3, ks=z&7); z==16 = ysum plane.
// ---------------------------------------------------------------------------
__global__ __launch_bounds__(256, 2) void layer2_kernel(
    const float* __restrict__ p1,
    const float* __restrict__ b1_mu, const float* __restrict__ b1_lv,
    const float* __restrict__ w2_mu, const float* __restrict__ w2_lv,
    const float* __restrict__ y,
    float* __restrict__ p2,
    double* __restrict__ Sy, double* __restrict__ Sy2,
    double* __restrict__ accum, unsigned int* __restrict__ counter)
{
    __shared__ float Hc[32][68];    // [m][k] 64+4 pad
    const int t = threadIdx.x;

    if (blockIdx.z == 16) {
        // ----- ysum plane: 16 blocks, 8 dims each -----
        const int id = blockIdx.x;
        const int dl = t & 7;
        const int g  = t >> 3;               // 0..31, 16 rows each
        const int d  = id * 8 + dl;
        float s = 0.f, s2 = 0.f;
        #pragma unroll
        for (int i = g * 16; i < g * 16 + 16; ++i) {
            const float v = y[i * YD + d];
            s += v; s2 += v * v;
        }
        float* shs  = &Hc[0][0];             // 2176 floats available
        float* shs2 = &Hc[0][0] + 512;
        shs[t] = s; shs2[t] = s2;
        __syncthreads();
        if (t < 8) {
            double S = 0.0, S2 = 0.0;
            #pragma unroll
            for (int gg = 0; gg < 32; ++gg) {
                S += (double)shs[gg * 8 + t]; S2 += (double)shs2[gg * 8 + t];
            }
            Sy[id * 8 + t] = S; Sy2[id * 8 + t] = S2;
        } else if (id == 0 && t == 8)  { accum[0] = 0.0; }
        else if (id == 0 && t == 9)  { accum[1] = 0.0; }
        else if (id == 0 && t == 10) { *counter = 0u; }
        return;
    }

    // ----- GEMM planes -----
    const int branch = blockIdx.z >> 3;
    const int ks     = blockIdx.z & 7;
    const float* __restrict__ q  = p1 + (size_t)(branch * 4) * (BSZ * H2D);
    const float* __restrict__ b1 = branch ? b1_lv : b1_mu;
    const float* __restrict__ W  = branch ? w2_lv : w2_mu;
    float* __restrict__ out = p2 + (size_t)blockIdx.z * (BSZ * YD);

    const int m0   = blockIdx.x * 32;
    const int kb   = ks * 64;
    const int lane = t & 63;
    const int wave = t >> 6;

    // Stage H chunk 32m x 64k: row = t>>3 (0..31), kq = (t&7)*8 (2 float4).
    // Sum 4 p1 slices + bias, relu.
    {
        const int row  = t >> 3;
        const int kq   = (t & 7) * 8;
        const int base = (m0 + row) * H2D + kb + kq;
        float4 h0 = *(const float4*)&b1[kb + kq];
        float4 h1 = *(const float4*)&b1[kb + kq + 4];
        #pragma unroll
        for (int s = 0; s < 4; ++s) {
            const float4 v0 = *(const float4*)&q[(size_t)s * (BSZ * H2D) + base];
            const float4 v1 = *(const float4*)&q[(size_t)s * (BSZ * H2D) + base + 4];
            h0.x += v0.x; h0.y += v0.y; h0.z += v0.z; h0.w += v0.w;
            h1.x += v1.x; h1.y += v1.y; h1.z += v1.z; h1.w += v1.w;
        }
        h0.x = fmaxf(h0.x, 0.f); h0.y = fmaxf(h0.y, 0.f);
        h0.z = fmaxf(h0.z, 0.f); h0.w = fmaxf(h0.w, 0.f);
        h1.x = fmaxf(h1.x, 0.f); h1.y = fmaxf(h1.y, 0.f);
        h1.z = fmaxf(h1.z, 0.f); h1.w = fmaxf(h1.w, 0.f);
        *(float4*)&Hc[row][kq]     = h0;
        *(float4*)&Hc[row][kq + 4] = h1;
    }
    __syncthreads();

    // Compute: wave owns m-rows wave*8..+7. B-chunk in registers, two 32-k
    // halves to bound live VGPRs.
    const int wm0 = wave * 8;
    float acc0[8] = {}, acc1[8] = {};
    #pragma unroll
    for (int half = 0; half < 2; ++half) {
        const int kh = kb + half * 32;
        float br0[32], br1[32];
        #pragma unroll
        for (int k = 0; k < 32; ++k) {
            br0[k] = W[(kh + k) * YD + lane];
            br1[k] = W[(kh + k) * YD + 64 + lane];
        }
        #pragma unroll
        for (int m = 0; m < 8; ++m) {
            const float* hrow = &Hc[wm0 + m][half * 32];
            #pragma unroll
            for (int qd = 0; qd < 8; ++qd) {
                const float4 a4 = *(const float4*)&hrow[qd * 4];
                acc0[m] += a4.x * br0[qd * 4 + 0]; acc1[m] += a4.x * br1[qd * 4 + 0];
                acc0[m] += a4.y * br0[qd * 4 + 1]; acc1[m] += a4.y * br1[qd * 4 + 1];
                acc0[m] += a4.z * br0[qd * 4 + 2]; acc1[m] += a4.z * br1[qd * 4 + 2];
                acc0[m] += a4.w * br0[qd * 4 + 3]; acc1[m] += a4.w * br1[qd * 4 + 3];
            }
        }
    }

    #pragma unroll
    for (int m = 0; m < 8; ++m) {
        const int row = (m0 + wm0 + m) * YD;
        out[row + lane]      = acc0[m];
        out[row + 64 + lane] = acc1[m];
    }
}

// ---------------------------------------------------------------------------
// reduce (+inline finalize): per element e=(i,d):
//   mu = sum_{s<8} p2[s][e] + b2_mu[d]; lv = tanh(sum_{s>=8} p2[s][e] + b2_lv[d])
//   iv = exp(-lv)
//   pos += -0.5*(mu-y)^2*iv - 0.5*lv
//   ap  += iv*(-0.5*Sy2[d] + mu*Sy[d] - 256*mu^2) - 256*lv
// fp32 elementwise, fp64 block reduction + device atomics; last block (atomic
// counter) finalizes: out = pos/B - ap/B^2 - log1p(exp(-20)/(B-1)).
// ---------------------------------------------------------------------------
__global__ __launch_bounds__(256) void reduce_kernel(
    const float* __restrict__ p2, const float* __restrict__ y,
    const float* __restrict__ b2_mu, const float* __restrict__ b2_lv,
    const double* __restrict__ Sy, const double* __restrict__ Sy2,
    double* __restrict__ accum, unsigned int* __restrict__ counter,
    float* __restrict__ outp)
{
    const int NE = BSZ * YD;
    const int e  = blockIdx.x * 256 + threadIdx.x;   // grid 256 covers exactly
    const int d  = e & (YD - 1);

    float mu = b2_mu[d];
    float lp = b2_lv[d];
    #pragma unroll
    for (int s = 0; s < 8; ++s) {
        mu += p2[s * NE + e];
        lp += p2[(8 + s) * NE + e];
    }
    const float lv = tanhf(lp);
    const float iv = expf(-lv);
    const float dm = mu - y[e];

    double pos = -0.5 * (double)dm * (double)dm * (double)iv - 0.5 * (double)lv;
    double ap  = (double)iv * (-0.5 * Sy2[d] + (double)mu * Sy[d]
                               - 256.0 * (double)mu * (double)mu)
               - 256.0 * (double)lv;

    #pragma unroll
    for (int off = 32; off > 0; off >>= 1) {
        pos += __shfl_down(pos, off);
        ap  += __shfl_down(ap, off);
    }
    __shared__ double sp[4];
    __shared__ double sa[4];
    const int lane = threadIdx.x & 63;
    const int wv   = threadIdx.x >> 6;
    if (lane == 0) { sp[wv] = pos; sa[wv] = ap; }
    __syncthreads();
    if (threadIdx.x == 0) {
        atomicAdd(&accum[0], sp[0] + sp[1] + sp[2] + sp[3]);
        atomicAdd(&accum[1], sa[0] + sa[1] + sa[2] + sa[3]);
        __threadfence();
        const unsigned int old = atomicAdd(counter, 1u);
        if (old == 255u) {                 // last block: finalize
            const double P = atomicAdd(&accum[0], 0.0);   // coherent read-back
            const double A = atomicAdd(&accum[1], 0.0);
            const double C = log1p(exp(-20.0) / 511.0);
            outp[0] = (float)(P / 512.0 - A / 262144.0 - C);
        }
    }
}

extern "C" void kernel_launch(void* const* d_in, const int* in_sizes, int n_in,
                              void* d_out, int out_size, void* d_ws, size_t ws_size,
                              hipStream_t stream) {
    const float* x     = (const float*)d_in[0];
    const float* y     = (const float*)d_in[1];
    const float* w1_mu = (const float*)d_in[2];
    const float* b1_mu = (const float*)d_in[3];
    const float* w2_mu = (const float*)d_in[4];
    const float* b2_mu = (const float*)d_in[5];
    const float* w1_lv = (const float*)d_in[6];
    const float* b1_lv = (const float*)d_in[7];
    const float* w2_lv = (const float*)d_in[8];
    const float* b2_lv = (const float*)d_in[9];

    char* ws = (char*)d_ws;
    float*  p1 = (float*)(ws);                                     // 8 MB (8 slices 512x512)
    float*  p2 = (float*)(ws + (size_t)8 * BSZ * H2D * 4);         // 4 MB (16 slices 512x128)
    double* Sy = (double*)(ws + (size_t)8 * BSZ * H2D * 4
                              + (size_t)16 * BSZ * YD * 4);        // 1 KB
    double* Sy2 = Sy + YD;                                         // 1 KB
    double* accum = Sy2 + YD;                                      // 16 B
    unsigned int* counter = (unsigned int*)(accum + 2);            // 4 B

    layer1_kernel<<<dim3(8, 8, 8), 256, 0, stream>>>(x, w1_mu, w1_lv, p1);
    layer2_kernel<<<dim3(16, 1, 17), 256, 0, stream>>>(
        p1, b1_mu, b1_lv, w2_mu, w2_lv, y, p2, Sy, Sy2, accum, counter);
    reduce_kernel<<<256, 256, 0, stream>>>(
        p2, y, b2_mu, b2_lv, Sy, Sy2, accum, counter, (float*)d_out);
}